// Round 3
// baseline (121.207 us; speedup 1.0000x reference)
//
#include <hip/hip_runtime.h>
#include <math.h>

#define RES 128
#define TOPK 16
#define NPTS 192
#define NQ 64                    // 4 tasks * 16 points
#define SIGMA_F (6.0f / 128.0f)
#define INV2S2 (1.0f / (2.0f * SIGMA_F * SIGMA_F))
#define NBLK 1024                // main kernel blocks
#define NWAVE (NBLK * 4)
#define NPAIRS (RES * RES)
#define TAB_OFF 4096             // float offset of tables in ws
#define TABN (NQ * RES)          // 8192 floats per table

// ---------------------------------------------------------------------------
// Kernel 1: prep. 1 block, 256 threads, wave = task.
// Rank-based top-16 (exact lax.top_k tie semantics: count of strictly-greater
// plus equal-with-lower-index), renormalize, per-axis bounds, then emit
// Gaussian axis tables to ws in [i][q] layout (X table has weight folded in).
// task: 0 = set1/b0, 1 = set1/b1, 2 = set2/b0, 3 = set2/b1
// ---------------------------------------------------------------------------
__global__ __launch_bounds__(256) void iou_prep(
    const float* __restrict__ pts1, const float* __restrict__ w1,
    const float* __restrict__ pts2, const float* __restrict__ w2,
    float* __restrict__ ws)
{
    __shared__ float swall[4][NPTS];
    __shared__ float sval[4][TOPK];
    __shared__ int   sidx[4][TOPK];
    __shared__ float sp[NQ][3];
    __shared__ float sw[NQ];
    __shared__ float sbound[6];      // lo x,y,z ; hi x,y,z

    const int tid  = threadIdx.x;
    const int lane = tid & 63;
    const int wave = tid >> 6;       // task id
    const int set  = wave >> 1;
    const int b    = wave & 1;

    const float* w   = (set ? w2 : w1) + b * NPTS;
    const float* pts = (set ? pts2 : pts1) + b * NPTS * 3;

    // each lane holds 3 of the 192 weights
    const float v0 = w[lane];
    const float v1 = w[lane + 64];
    const float v2 = w[lane + 128];
    swall[wave][lane]       = v0;
    swall[wave][lane + 64]  = v1;
    swall[wave][lane + 128] = v2;
    __syncthreads();

    // rank of each held element among all 192 (unique ranks, top_k order)
    int r0 = 0, r1 = 0, r2 = 0;
    for (int j = 0; j < NPTS; ++j) {
        const float wj = swall[wave][j];
        r0 += (wj > v0) || (wj == v0 && j < lane);
        r1 += (wj > v1) || (wj == v1 && j < lane + 64);
        r2 += (wj > v2) || (wj == v2 && j < lane + 128);
    }
    if (r0 < TOPK) { sval[wave][r0] = v0; sidx[wave][r0] = lane; }
    if (r1 < TOPK) { sval[wave][r1] = v1; sidx[wave][r1] = lane + 64; }
    if (r2 < TOPK) { sval[wave][r2] = v2; sidx[wave][r2] = lane + 128; }
    __syncthreads();

    // renormalize + gather selected points
    {
        float v = (lane < TOPK) ? sval[wave][lane] : 0.0f;
        float s = v;
        #pragma unroll
        for (int m = 32; m; m >>= 1) s += __shfl_xor(s, m, 64);
        if (lane < TOPK) {
            const int q   = wave * TOPK + lane;
            const int idx = sidx[wave][lane];
            sw[q]    = v / (s + 1e-5f);
            sp[q][0] = pts[idx * 3 + 0];
            sp[q][1] = pts[idx * 3 + 1];
            sp[q][2] = pts[idx * 3 + 2];
        }
    }
    __syncthreads();

    // per-axis bounds over all 64 selected points, padded by 3*sigma
    if (tid < 6) {
        const int  axis  = tid % 3;
        const bool ismax = tid >= 3;
        float r = sp[0][axis];
        for (int q = 1; q < NQ; ++q) {
            const float v = sp[q][axis];
            r = ismax ? fmaxf(r, v) : fminf(r, v);
        }
        sbound[tid] = ismax ? (r + 3.0f * SIGMA_F) : (r - 3.0f * SIGMA_F);
    }
    __syncthreads();

    // axis tables, [i][q] layout: 3 * 128 * 64 entries
    for (int e = tid; e < 3 * TABN; e += 256) {
        const int axis = e / TABN;       // 0=X, 1=Y, 2=Z
        const int rem  = e - axis * TABN;
        const int i    = rem >> 6;       // grid index
        const int q    = rem & 63;       // point index
        const float lo = sbound[axis];
        const float hi = sbound[axis + 3];
        const float c  = lo + (float)i * (hi - lo) * (1.0f / 127.0f);
        const float d  = c - sp[q][axis];
        float g = __expf(-d * d * INV2S2);
        if (axis == 0) g *= sw[q];       // fold weight into X table
        ws[TAB_OFF + e] = g;
    }
}

// ---------------------------------------------------------------------------
// Kernel 2: main sweep. No LDS. Work unit = (pair, z-half); each wave fixes
// one z-half (zq[64] in regs, 64 VGPRs) and walks 8 pairs. X/Y rows are
// wave-uniform reads from L2-resident tables.
// ---------------------------------------------------------------------------
__global__ __launch_bounds__(256) void iou_main(
    const float* __restrict__ ws, float* __restrict__ partials)
{
    const float* __restrict__ tabX = ws + TAB_OFF;
    const float* __restrict__ tabY = tabX + TABN;
    const float* __restrict__ tabZ = tabY + TABN;

    const int lane = threadIdx.x & 63;
    const int wid  = threadIdx.x >> 6;
    const int gw   = __builtin_amdgcn_readfirstlane(blockIdx.x * 4 + wid);
    const int h    = gw & 1;         // z half
    const int pb   = gw >> 1;        // pair base, [0, 2048)

    // z fragment: iz = h*64 + lane; zq[q] contiguous per lane in [i][q] layout
    float zq[NQ];
    {
        const float4* __restrict__ src = (const float4*)&tabZ[(h * 64 + lane) * NQ];
        float4* dst = (float4*)zq;
        #pragma unroll
        for (int t = 0; t < 16; ++t) dst[t] = src[t];
    }

    float Iacc = 0.0f, Uacc = 0.0f;

    #pragma unroll 1
    for (int k = 0; k < 8; ++k) {
        const int p  = pb + k * 2048;
        const int ix = p >> 7;
        const int iy = p & 127;
        const float4* __restrict__ px = (const float4*)&tabX[ix * NQ];
        const float4* __restrict__ py = (const float4*)&tabY[iy * NQ];

        // q-groups of 16: g 0-3 -> task0, 4-7 -> task1, 8-11 -> task2, 12-15 -> task3
        float acc0 = 0.0f, acc1 = 0.0f, acc2 = 0.0f, acc3 = 0.0f;
        #pragma unroll 4
        for (int g = 0; g < 16; ++g) {
            const float4 xv = px[g];
            const float4 yv = py[g];
            const int q = g * 4;
            const float s = (xv.x * yv.x) * zq[q]
                          + (xv.y * yv.y) * zq[q + 1]
                          + (xv.z * yv.z) * zq[q + 2]
                          + (xv.w * yv.w) * zq[q + 3];
            if      (g < 4)  acc0 += s;
            else if (g < 8)  acc1 += s;
            else if (g < 12) acc2 += s;
            else             acc3 += s;
        }
        // (acc0,acc1) = heatmap1 b0/b1, (acc2,acc3) = heatmap2 b0/b1
        const float p0 = acc0 * acc2;
        const float p1 = acc1 * acc3;
        Iacc += p0 + p1;
        Uacc += (acc0 + acc2 - p0) + (acc1 + acc3 - p1);
    }

    // wave reduce, then block reduce
    #pragma unroll
    for (int m = 32; m; m >>= 1) {
        Iacc += __shfl_xor(Iacc, m, 64);
        Uacc += __shfl_xor(Uacc, m, 64);
    }
    __shared__ float rI[4], rU[4];
    if (lane == 0) { rI[wid] = Iacc; rU[wid] = Uacc; }
    __syncthreads();
    if (threadIdx.x == 0) {
        partials[blockIdx.x]        = rI[0] + rI[1] + rI[2] + rI[3];
        partials[NBLK + blockIdx.x] = rU[0] + rU[1] + rU[2] + rU[3];
    }
}

// ---------------------------------------------------------------------------
// Kernel 3: deterministic final reduce of NBLK partial pairs -> scalar loss.
// ---------------------------------------------------------------------------
__global__ __launch_bounds__(256) void iou_final(
    const float* __restrict__ ws, float* __restrict__ out)
{
    __shared__ float rI[4], rU[4];
    const int tid  = threadIdx.x;
    const int lane = tid & 63;
    const int wid  = tid >> 6;

    float I = 0.0f, U = 0.0f;
    for (int i = tid; i < NBLK; i += 256) {
        I += ws[i];
        U += ws[NBLK + i];
    }
    #pragma unroll
    for (int m = 32; m; m >>= 1) {
        I += __shfl_xor(I, m, 64);
        U += __shfl_xor(U, m, 64);
    }
    if (lane == 0) { rI[wid] = I; rU[wid] = U; }
    __syncthreads();
    if (tid == 0) {
        const float It = rI[0] + rI[1] + rI[2] + rI[3];
        const float Ut = rU[0] + rU[1] + rU[2] + rU[3] + 1e-5f;
        out[0] = 1.0f - It / Ut;
    }
}

extern "C" void kernel_launch(void* const* d_in, const int* in_sizes, int n_in,
                              void* d_out, int out_size, void* d_ws, size_t ws_size,
                              hipStream_t stream)
{
    const float* pts1 = (const float*)d_in[0];   // [2,192,3]
    const float* w1   = (const float*)d_in[1];   // [2,192]
    const float* pts2 = (const float*)d_in[2];   // [2,192,3]
    const float* w2   = (const float*)d_in[3];   // [2,192]
    float* out = (float*)d_out;                  // scalar
    float* ws  = (float*)d_ws;                   // >= (TAB_OFF + 3*TABN) floats

    iou_prep <<<1,    256, 0, stream>>>(pts1, w1, pts2, w2, ws);
    iou_main <<<NBLK, 256, 0, stream>>>(ws, ws);
    iou_final<<<1,    256, 0, stream>>>(ws, out);
}

// Round 4
// 49.999 us; speedup vs baseline: 2.4242x; 2.4242x over previous
//
#include <hip/hip_runtime.h>
#include <math.h>

#define RES 128
#define TOPK 16
#define NPTS 192
#define NQ 64                    // 4 tasks * 16 points
#define SIGMA_F (6.0f / 128.0f)
#define INV2S2 (1.0f / (2.0f * SIGMA_F * SIGMA_F))
#define NBLK 1024                // main kernel blocks
#define NPAIRS (RES * RES)
#define TAB_OFF 4096             // float offset of tables in ws
#define TABN (NQ * RES)          // 8192 floats per table

// ---------------------------------------------------------------------------
// Kernel 1: prep. 1 block, 256 threads, wave = task.
// Rank-based top-16 (exact lax.top_k tie semantics), renormalize, per-axis
// bounds, Gaussian axis tables to ws in [i][q] layout (weight folded into X).
// task: 0 = set1/b0, 1 = set1/b1, 2 = set2/b0, 3 = set2/b1
// ---------------------------------------------------------------------------
__global__ __launch_bounds__(256) void iou_prep(
    const float* __restrict__ pts1, const float* __restrict__ w1,
    const float* __restrict__ pts2, const float* __restrict__ w2,
    float* __restrict__ ws)
{
    __shared__ float swall[4][NPTS];
    __shared__ float sval[4][TOPK];
    __shared__ int   sidx[4][TOPK];
    __shared__ float sp[NQ][3];
    __shared__ float sw[NQ];
    __shared__ float sbound[6];      // lo x,y,z ; hi x,y,z

    const int tid  = threadIdx.x;
    const int lane = tid & 63;
    const int wave = tid >> 6;       // task id
    const int set  = wave >> 1;
    const int b    = wave & 1;

    const float* w   = (set ? w2 : w1) + b * NPTS;
    const float* pts = (set ? pts2 : pts1) + b * NPTS * 3;

    const float v0 = w[lane];
    const float v1 = w[lane + 64];
    const float v2 = w[lane + 128];
    swall[wave][lane]       = v0;
    swall[wave][lane + 64]  = v1;
    swall[wave][lane + 128] = v2;
    __syncthreads();

    // rank among all 192 (strictly-greater, or equal with lower index)
    int r0 = 0, r1 = 0, r2 = 0;
    for (int j = 0; j < NPTS; ++j) {
        const float wj = swall[wave][j];
        r0 += (wj > v0) || (wj == v0 && j < lane);
        r1 += (wj > v1) || (wj == v1 && j < lane + 64);
        r2 += (wj > v2) || (wj == v2 && j < lane + 128);
    }
    if (r0 < TOPK) { sval[wave][r0] = v0; sidx[wave][r0] = lane; }
    if (r1 < TOPK) { sval[wave][r1] = v1; sidx[wave][r1] = lane + 64; }
    if (r2 < TOPK) { sval[wave][r2] = v2; sidx[wave][r2] = lane + 128; }
    __syncthreads();

    // renormalize + gather selected points
    {
        float v = (lane < TOPK) ? sval[wave][lane] : 0.0f;
        float s = v;
        #pragma unroll
        for (int m = 32; m; m >>= 1) s += __shfl_xor(s, m, 64);
        if (lane < TOPK) {
            const int q   = wave * TOPK + lane;
            const int idx = sidx[wave][lane];
            sw[q]    = v / (s + 1e-5f);
            sp[q][0] = pts[idx * 3 + 0];
            sp[q][1] = pts[idx * 3 + 1];
            sp[q][2] = pts[idx * 3 + 2];
        }
    }
    __syncthreads();

    // per-axis bounds over all 64 selected points, padded by 3*sigma
    if (tid < 6) {
        const int  axis  = tid % 3;
        const bool ismax = tid >= 3;
        float r = sp[0][axis];
        for (int q = 1; q < NQ; ++q) {
            const float v = sp[q][axis];
            r = ismax ? fmaxf(r, v) : fminf(r, v);
        }
        sbound[tid] = ismax ? (r + 3.0f * SIGMA_F) : (r - 3.0f * SIGMA_F);
    }
    __syncthreads();

    // axis tables, [i][q] layout: 3 * 128 * 64 entries
    for (int e = tid; e < 3 * TABN; e += 256) {
        const int axis = e / TABN;       // 0=X, 1=Y, 2=Z
        const int rem  = e - axis * TABN;
        const int i    = rem >> 6;       // grid index
        const int q    = rem & 63;       // point index
        const float lo = sbound[axis];
        const float hi = sbound[axis + 3];
        const float c  = lo + (float)i * (hi - lo) * (1.0f / 127.0f);
        const float d  = c - sp[q][axis];
        float g = __expf(-d * d * INV2S2);
        if (axis == 0) g *= sw[q];       // fold weight into X table
        ws[TAB_OFF + e] = g;
    }
}

// ---------------------------------------------------------------------------
// Kernel 2: main sweep. Work unit = (pair, z-half). Each wave holds one
// z-half in regs (zq[64], ALL indices compile-time constant -> registers),
// walks 8 pairs. X/Y rows are wave-uniform L2 reads.
// ---------------------------------------------------------------------------

// Section T (T = literal 0..3): q in [T*16, T*16+16) -> one task's heatmap.
// Inner loop has known trip count 4 and full unroll -> all zq indices static.
#define SEC(T, ACC) {                                                        \
    float s_ = 0.0f;                                                         \
    _Pragma("unroll")                                                        \
    for (int g = 0; g < 4; ++g) {                                            \
        const float4 xv = px[(T)*4 + g];                                     \
        const float4 yv = py[(T)*4 + g];                                     \
        s_ += (xv.x * yv.x) * zq[(T)*16 + g*4 + 0]                           \
            + (xv.y * yv.y) * zq[(T)*16 + g*4 + 1]                           \
            + (xv.z * yv.z) * zq[(T)*16 + g*4 + 2]                           \
            + (xv.w * yv.w) * zq[(T)*16 + g*4 + 3];                          \
    }                                                                        \
    ACC = s_;                                                                \
}

__global__ __launch_bounds__(256, 4) void iou_main(
    const float* __restrict__ ws, float* __restrict__ partials)
{
    const float* __restrict__ tabX = ws + TAB_OFF;
    const float* __restrict__ tabY = tabX + TABN;
    const float* __restrict__ tabZ = tabY + TABN;

    const int lane = threadIdx.x & 63;
    const int wid  = threadIdx.x >> 6;
    const int gw   = __builtin_amdgcn_readfirstlane(blockIdx.x * 4 + wid);
    const int h    = gw & 1;         // z half
    const int pb   = gw >> 1;        // pair base, [0, 2048)

    // z fragment: iz = h*64 + lane; [i][q] layout -> 64 contiguous floats
    float zq[NQ];
    {
        const float4* __restrict__ src = (const float4*)&tabZ[(h * 64 + lane) * NQ];
        float4* dst = (float4*)zq;
        #pragma unroll
        for (int t = 0; t < 16; ++t) dst[t] = src[t];
    }

    float Iacc = 0.0f, Uacc = 0.0f;

    #pragma unroll 1
    for (int k = 0; k < 8; ++k) {
        const int p  = pb + k * 2048;
        const int ix = p >> 7;
        const int iy = p & 127;
        const float4* __restrict__ px = (const float4*)&tabX[ix * NQ];
        const float4* __restrict__ py = (const float4*)&tabY[iy * NQ];

        float acc0, acc1, acc2, acc3;
        SEC(0, acc0)   // heatmap1 b0
        SEC(1, acc1)   // heatmap1 b1
        SEC(2, acc2)   // heatmap2 b0
        SEC(3, acc3)   // heatmap2 b1

        const float p0 = acc0 * acc2;
        const float p1 = acc1 * acc3;
        Iacc += p0 + p1;
        Uacc += (acc0 + acc2 - p0) + (acc1 + acc3 - p1);
    }

    // wave reduce, then block reduce
    #pragma unroll
    for (int m = 32; m; m >>= 1) {
        Iacc += __shfl_xor(Iacc, m, 64);
        Uacc += __shfl_xor(Uacc, m, 64);
    }
    __shared__ float rI[4], rU[4];
    if (lane == 0) { rI[wid] = Iacc; rU[wid] = Uacc; }
    __syncthreads();
    if (threadIdx.x == 0) {
        partials[blockIdx.x]        = rI[0] + rI[1] + rI[2] + rI[3];
        partials[NBLK + blockIdx.x] = rU[0] + rU[1] + rU[2] + rU[3];
    }
}

// ---------------------------------------------------------------------------
// Kernel 3: deterministic final reduce of NBLK partial pairs -> scalar loss.
// ---------------------------------------------------------------------------
__global__ __launch_bounds__(256) void iou_final(
    const float* __restrict__ ws, float* __restrict__ out)
{
    __shared__ float rI[4], rU[4];
    const int tid  = threadIdx.x;
    const int lane = tid & 63;
    const int wid  = tid >> 6;

    float I = 0.0f, U = 0.0f;
    for (int i = tid; i < NBLK; i += 256) {
        I += ws[i];
        U += ws[NBLK + i];
    }
    #pragma unroll
    for (int m = 32; m; m >>= 1) {
        I += __shfl_xor(I, m, 64);
        U += __shfl_xor(U, m, 64);
    }
    if (lane == 0) { rI[wid] = I; rU[wid] = U; }
    __syncthreads();
    if (tid == 0) {
        const float It = rI[0] + rI[1] + rI[2] + rI[3];
        const float Ut = rU[0] + rU[1] + rU[2] + rU[3] + 1e-5f;
        out[0] = 1.0f - It / Ut;
    }
}

extern "C" void kernel_launch(void* const* d_in, const int* in_sizes, int n_in,
                              void* d_out, int out_size, void* d_ws, size_t ws_size,
                              hipStream_t stream)
{
    const float* pts1 = (const float*)d_in[0];   // [2,192,3]
    const float* w1   = (const float*)d_in[1];   // [2,192]
    const float* pts2 = (const float*)d_in[2];   // [2,192,3]
    const float* w2   = (const float*)d_in[3];   // [2,192]
    float* out = (float*)d_out;                  // scalar
    float* ws  = (float*)d_ws;                   // >= (TAB_OFF + 3*TABN) floats

    iou_prep <<<1,    256, 0, stream>>>(pts1, w1, pts2, w2, ws);
    iou_main <<<NBLK, 256, 0, stream>>>(ws, ws);
    iou_final<<<1,    256, 0, stream>>>(ws, out);
}

// Round 5
// 48.660 us; speedup vs baseline: 2.4909x; 1.0275x over previous
//
#include <hip/hip_runtime.h>
#include <math.h>

#define RES 128
#define TOPK 16
#define NPTS 192
#define NQ 64                    // 4 tasks * 16 points
#define SIGMA_F (6.0f / 128.0f)
#define INV2S2 (1.0f / (2.0f * SIGMA_F * SIGMA_F))
#define NBLK 512                 // fused kernel blocks (2/CU, fully resident)
#define NPAIRS (RES * RES)
#define CTR_OFF 8                // u32 index of done-counter in ws
#define PART_OFF 16              // float index of partials in ws

// ---------------------------------------------------------------------------
// Micro-kernel: zero the done-counter (ws is harness-poisoned, can't rely on it).
// ---------------------------------------------------------------------------
__global__ void iou_ctr_zero(unsigned* __restrict__ ws_u) { ws_u[CTR_OFF] = 0u; }

// ---------------------------------------------------------------------------
// Fused kernel. Every block redundantly: rank-based top-16 per task (wave=task),
// renorm, bounds, X/Y Gaussian tables -> LDS [i][q] (weight folded into X),
// per-wave z-fragment zq[64] in regs via __expf. Then each wave sweeps 16
// (ix,iy) pairs for its z-half; X/Y rows are LDS broadcast ds_read_b128.
// Block partials -> ws; last finishing block (device-scope atomic counter)
// reduces all partials and writes the scalar loss.
// task: 0 = set1/b0, 1 = set1/b1, 2 = set2/b0, 3 = set2/b1
// ---------------------------------------------------------------------------

// Section T (T literal 0..3): q in [T*16, T*16+16) -> one task's heatmap.
// All zq indices compile-time constant -> registers (rule #20).
#define SEC(T, ACC) {                                                        \
    float s_ = 0.0f;                                                         \
    _Pragma("unroll")                                                        \
    for (int g = 0; g < 4; ++g) {                                            \
        const float4 xv = px[(T)*4 + g];                                     \
        const float4 yv = py[(T)*4 + g];                                     \
        s_ += (xv.x * yv.x) * zq[(T)*16 + g*4 + 0]                           \
            + (xv.y * yv.y) * zq[(T)*16 + g*4 + 1]                           \
            + (xv.z * yv.z) * zq[(T)*16 + g*4 + 2]                           \
            + (xv.w * yv.w) * zq[(T)*16 + g*4 + 3];                          \
    }                                                                        \
    ACC = s_;                                                                \
}

__global__ __launch_bounds__(256, 2) void iou_fused(
    const float* __restrict__ pts1, const float* __restrict__ w1,
    const float* __restrict__ pts2, const float* __restrict__ w2,
    float* __restrict__ ws, float* __restrict__ out)
{
    __shared__ float tX[RES * NQ];     // 32 KB, [i][q]
    __shared__ float tY[RES * NQ];     // 32 KB, [i][q]
    __shared__ float swall[4][NPTS];
    __shared__ float sval[4][TOPK];
    __shared__ int   sidx[4][TOPK];
    __shared__ float sp[NQ][3];
    __shared__ float sw[NQ];
    __shared__ float sbound[6];        // lo x,y,z ; hi x,y,z
    __shared__ float rI[4], rU[4];
    __shared__ int   sdone;

    const int tid  = threadIdx.x;
    const int lane = tid & 63;
    const int wid  = tid >> 6;

    // ---- prep 1: rank-based top-16; wave == task ----
    {
        const int set = wid >> 1;
        const int b   = wid & 1;
        const float* w   = (set ? w2 : w1) + b * NPTS;
        const float* pts = (set ? pts2 : pts1) + b * NPTS * 3;

        const float v0 = w[lane];
        const float v1 = w[lane + 64];
        const float v2 = w[lane + 128];
        swall[wid][lane]       = v0;
        swall[wid][lane + 64]  = v1;
        swall[wid][lane + 128] = v2;
        __syncthreads();

        // rank among all 192: strictly-greater, or equal with lower index
        int r0 = 0, r1 = 0, r2 = 0;
        for (int j = 0; j < NPTS; ++j) {
            const float wj = swall[wid][j];
            r0 += (wj > v0) || (wj == v0 && j < lane);
            r1 += (wj > v1) || (wj == v1 && j < lane + 64);
            r2 += (wj > v2) || (wj == v2 && j < lane + 128);
        }
        if (r0 < TOPK) { sval[wid][r0] = v0; sidx[wid][r0] = lane; }
        if (r1 < TOPK) { sval[wid][r1] = v1; sidx[wid][r1] = lane + 64; }
        if (r2 < TOPK) { sval[wid][r2] = v2; sidx[wid][r2] = lane + 128; }
        __syncthreads();

        // renormalize + gather selected points
        float v = (lane < TOPK) ? sval[wid][lane] : 0.0f;
        float s = v;
        #pragma unroll
        for (int m = 32; m; m >>= 1) s += __shfl_xor(s, m, 64);
        if (lane < TOPK) {
            const int q   = wid * TOPK + lane;
            const int idx = sidx[wid][lane];
            sw[q]    = v / (s + 1e-5f);
            sp[q][0] = pts[idx * 3 + 0];
            sp[q][1] = pts[idx * 3 + 1];
            sp[q][2] = pts[idx * 3 + 2];
        }
    }
    __syncthreads();

    // ---- prep 2: per-axis bounds over all 64 selected points ----
    if (tid < 6) {
        const int  axis  = tid % 3;
        const bool ismax = tid >= 3;
        float r = sp[0][axis];
        for (int q = 1; q < NQ; ++q) {
            const float v = sp[q][axis];
            r = ismax ? fmaxf(r, v) : fminf(r, v);
        }
        sbound[tid] = ismax ? (r + 3.0f * SIGMA_F) : (r - 3.0f * SIGMA_F);
    }
    __syncthreads();

    // ---- prep 3a: X/Y tables -> LDS, [i][q] ----
    for (int e = tid; e < 2 * NQ * RES; e += 256) {
        const int isY = e >> 13;
        const int rem = e & 8191;
        const int i   = rem >> 6;
        const int q   = rem & 63;
        const float lo = sbound[isY];
        const float hi = sbound[isY + 3];
        const float c  = lo + (float)i * (hi - lo) * (1.0f / 127.0f);
        const float d  = c - sp[q][isY];
        float g = __expf(-d * d * INV2S2);
        if (!isY) g *= sw[q];            // fold weight into X table
        (isY ? tY : tX)[rem] = g;
    }

    // ---- prep 3b: z fragment in regs; wave's z-half h = wid&1 ----
    const int h  = wid & 1;
    const int pb = blockIdx.x * 2 + (wid >> 1);   // [0, 1024)
    float zq[NQ];
    {
        const float loz = sbound[2], hiz = sbound[5];
        const float cz  = loz + (float)(h * 64 + lane) * (hiz - loz) * (1.0f / 127.0f);
        #pragma unroll
        for (int q = 0; q < NQ; ++q) {
            const float d = cz - sp[q][2];
            zq[q] = __expf(-d * d * INV2S2);
        }
    }
    __syncthreads();

    // ---- sweep: 16 pairs per wave ----
    float Iacc = 0.0f, Uacc = 0.0f;
    #pragma unroll 1
    for (int k = 0; k < 16; ++k) {
        const int p  = pb + k * 1024;
        const int ix = p >> 7;
        const int iy = p & 127;
        const float4* px = (const float4*)&tX[ix * NQ];
        const float4* py = (const float4*)&tY[iy * NQ];

        float acc0, acc1, acc2, acc3;
        SEC(0, acc0)   // heatmap1 b0
        SEC(1, acc1)   // heatmap1 b1
        SEC(2, acc2)   // heatmap2 b0
        SEC(3, acc3)   // heatmap2 b1

        const float p0 = acc0 * acc2;
        const float p1 = acc1 * acc3;
        Iacc += p0 + p1;
        Uacc += (acc0 + acc2 - p0) + (acc1 + acc3 - p1);
    }

    // ---- block reduce ----
    #pragma unroll
    for (int m = 32; m; m >>= 1) {
        Iacc += __shfl_xor(Iacc, m, 64);
        Uacc += __shfl_xor(Uacc, m, 64);
    }
    if (lane == 0) { rI[wid] = Iacc; rU[wid] = Uacc; }
    __syncthreads();

    // ---- publish partials; last block reduces (device-scope, order-free) ----
    if (tid == 0) {
        ws[PART_OFF + blockIdx.x]        = rI[0] + rI[1] + rI[2] + rI[3];
        ws[PART_OFF + NBLK + blockIdx.x] = rU[0] + rU[1] + rU[2] + rU[3];
        __threadfence();                              // release partials
        const unsigned old = atomicAdd((unsigned*)ws + CTR_OFF, 1u);
        sdone = (old == NBLK - 1u);
    }
    __syncthreads();

    if (sdone) {
        __threadfence();                              // acquire others' partials
        float I = 0.0f, U = 0.0f;
        for (int i = tid; i < NBLK; i += 256) {
            I += ws[PART_OFF + i];
            U += ws[PART_OFF + NBLK + i];
        }
        #pragma unroll
        for (int m = 32; m; m >>= 1) {
            I += __shfl_xor(I, m, 64);
            U += __shfl_xor(U, m, 64);
        }
        __syncthreads();                              // reuse rI/rU safely
        if (lane == 0) { rI[wid] = I; rU[wid] = U; }
        __syncthreads();
        if (tid == 0) {
            const float It = rI[0] + rI[1] + rI[2] + rI[3];
            const float Ut = rU[0] + rU[1] + rU[2] + rU[3] + 1e-5f;
            out[0] = 1.0f - It / Ut;
        }
    }
}

extern "C" void kernel_launch(void* const* d_in, const int* in_sizes, int n_in,
                              void* d_out, int out_size, void* d_ws, size_t ws_size,
                              hipStream_t stream)
{
    const float* pts1 = (const float*)d_in[0];   // [2,192,3]
    const float* w1   = (const float*)d_in[1];   // [2,192]
    const float* pts2 = (const float*)d_in[2];   // [2,192,3]
    const float* w2   = (const float*)d_in[3];   // [2,192]
    float* out = (float*)d_out;                  // scalar
    float* ws  = (float*)d_ws;

    iou_ctr_zero<<<1, 1, 0, stream>>>((unsigned*)ws);
    iou_fused<<<NBLK, 256, 0, stream>>>(pts1, w1, pts2, w2, ws, out);
}

// Round 6
// 32.933 us; speedup vs baseline: 3.6804x; 1.4775x over previous
//
#include <hip/hip_runtime.h>
#include <math.h>

#define RES 128
#define TOPK 16
#define NPTS 192
#define NQ 64                    // 4 tasks * 16 points
#define SIGMA_F (6.0f / 128.0f)
#define INV2S2 (1.0f / (2.0f * SIGMA_F * SIGMA_F))
#define GPITCH 132               // G row pitch in floats (128 + 4 pad, 16B-aligned)

// ---------------------------------------------------------------------------
// Single-block fused kernel using separability of the tensor-product grid:
//   I  = sum_v h1*h2 = sum_{q,q'} Cx[q][q'] * Cy[q][q'] * Cz[q][q']
//   S1 = sum_v h1    = sum_q Sx[q]*Sy[q]*Sz[q]   (w folded into axis-0 table)
//   U  = S1 + S2 - I ;  loss = 1 - I/(U + 1e-5)
// where C*[q][q'] = sum_i G*[q][i] * G*[q'][i] over the 128-point axis grid.
// Cross pairs: batch0 = task0 x task2, batch1 = task1 x task3 (16x16 each).
//
// Phases: (1) rank-based top-16 per task (wave=task) + renorm + gather,
// (2) per-axis bounds, (3) loop axis=0..2: build G[64][128] in LDS, then
// each thread multiplies its 2 cross-dot accumulators (and, for tid<64, its
// self-sum accumulator) by this axis's dot, (4) block reduce, scalar out.
// task: 0 = set1/b0, 1 = set1/b1, 2 = set2/b0, 3 = set2/b1
// ---------------------------------------------------------------------------
__global__ __launch_bounds__(256) void iou_sep(
    const float* __restrict__ pts1, const float* __restrict__ w1,
    const float* __restrict__ pts2, const float* __restrict__ w2,
    float* __restrict__ out)
{
    __shared__ float Gf[NQ * GPITCH];   // 33.8 KB, rebuilt per axis
    __shared__ float swall[4][NPTS];
    __shared__ float sval[4][TOPK];
    __shared__ int   sidx[4][TOPK];
    __shared__ float sp[NQ][3];
    __shared__ float sw[NQ];
    __shared__ float sbound[6];         // lo x,y,z ; hi x,y,z
    __shared__ float rI[4];
    __shared__ float sS1, sS2;

    const int tid  = threadIdx.x;
    const int lane = tid & 63;
    const int wid  = tid >> 6;

    // ---- phase 1: rank-based top-16; wave == task ----
    {
        const int set = wid >> 1;
        const int b   = wid & 1;
        const float* w   = (set ? w2 : w1) + b * NPTS;
        const float* pts = (set ? pts2 : pts1) + b * NPTS * 3;

        const float v0 = w[lane];
        const float v1 = w[lane + 64];
        const float v2 = w[lane + 128];
        swall[wid][lane]       = v0;
        swall[wid][lane + 64]  = v1;
        swall[wid][lane + 128] = v2;
        __syncthreads();

        // rank among all 192: strictly-greater, or equal with lower index
        int r0 = 0, r1 = 0, r2 = 0;
        for (int j = 0; j < NPTS; ++j) {
            const float wj = swall[wid][j];
            r0 += (wj > v0) || (wj == v0 && j < lane);
            r1 += (wj > v1) || (wj == v1 && j < lane + 64);
            r2 += (wj > v2) || (wj == v2 && j < lane + 128);
        }
        if (r0 < TOPK) { sval[wid][r0] = v0; sidx[wid][r0] = lane; }
        if (r1 < TOPK) { sval[wid][r1] = v1; sidx[wid][r1] = lane + 64; }
        if (r2 < TOPK) { sval[wid][r2] = v2; sidx[wid][r2] = lane + 128; }
        __syncthreads();

        // renormalize + gather selected points
        float v = (lane < TOPK) ? sval[wid][lane] : 0.0f;
        float s = v;
        #pragma unroll
        for (int m = 32; m; m >>= 1) s += __shfl_xor(s, m, 64);
        if (lane < TOPK) {
            const int q   = wid * TOPK + lane;
            const int idx = sidx[wid][lane];
            sw[q]    = v / (s + 1e-5f);
            sp[q][0] = pts[idx * 3 + 0];
            sp[q][1] = pts[idx * 3 + 1];
            sp[q][2] = pts[idx * 3 + 2];
        }
    }
    __syncthreads();

    // ---- phase 2: per-axis bounds over all 64 selected points ----
    if (tid < 6) {
        const int  axis  = tid % 3;
        const bool ismax = tid >= 3;
        float r = sp[0][axis];
        for (int q = 1; q < NQ; ++q) {
            const float v = sp[q][axis];
            r = ismax ? fmaxf(r, v) : fminf(r, v);
        }
        sbound[tid] = ismax ? (r + 3.0f * SIGMA_F) : (r - 3.0f * SIGMA_F);
    }
    __syncthreads();

    // ---- phase 3: per-axis build + dot, multiplicative accumulate ----
    // Cross pair p (p in [0,512)): batch = p>>8, ql = (p>>4)&15, qr = p&15
    //   q = batch*16 + ql  (set1),  q' = 32 + batch*16 + qr  (set2)
    const int p0 = tid;          // pair 0
    const int p1 = tid + 256;    // pair 1
    const int q0a = ((p0 >> 8) << 4) + ((p0 >> 4) & 15);
    const int q0b = 32 + ((p0 >> 8) << 4) + (p0 & 15);
    const int q1a = ((p1 >> 8) << 4) + ((p1 >> 4) & 15);
    const int q1b = 32 + ((p1 >> 8) << 4) + (p1 & 15);

    float cp0 = 1.0f, cp1 = 1.0f;    // cross-dot products across axes
    float sprod = 1.0f;              // self-sum product (tid < 64 only)

    #pragma unroll 1
    for (int axis = 0; axis < 3; ++axis) {
        // build G[q][i] for this axis (w folded in at axis 0)
        const float lo   = sbound[axis];
        const float step = (sbound[axis + 3] - lo) * (1.0f / 127.0f);
        for (int e = tid; e < NQ * RES; e += 256) {
            const int q = e >> 7;
            const int i = e & 127;
            const float c = lo + (float)i * step;
            const float d = c - sp[q][axis];
            float g = __expf(-d * d * INV2S2);
            if (axis == 0) g *= sw[q];
            Gf[q * GPITCH + i] = g;
        }
        __syncthreads();

        // two cross dots per thread
        {
            const float4* A = (const float4*)&Gf[q0a * GPITCH];
            const float4* B = (const float4*)&Gf[q0b * GPITCH];
            const float4* C = (const float4*)&Gf[q1a * GPITCH];
            const float4* D = (const float4*)&Gf[q1b * GPITCH];
            float4 a0 = {0,0,0,0}, a1 = {0,0,0,0};
            #pragma unroll 8
            for (int c = 0; c < 32; ++c) {
                const float4 x0 = A[c], y0 = B[c];
                const float4 x1 = C[c], y1 = D[c];
                a0.x += x0.x * y0.x; a0.y += x0.y * y0.y;
                a0.z += x0.z * y0.z; a0.w += x0.w * y0.w;
                a1.x += x1.x * y1.x; a1.y += x1.y * y1.y;
                a1.z += x1.z * y1.z; a1.w += x1.w * y1.w;
            }
            cp0 *= (a0.x + a0.y) + (a0.z + a0.w);
            cp1 *= (a1.x + a1.y) + (a1.z + a1.w);
        }
        // self sum for q = tid (tid < 64; whole wave 0, no divergence split)
        if (tid < 64) {
            const float4* A = (const float4*)&Gf[tid * GPITCH];
            float4 a = {0,0,0,0};
            #pragma unroll 8
            for (int c = 0; c < 32; ++c) {
                const float4 x = A[c];
                a.x += x.x; a.y += x.y; a.z += x.z; a.w += x.w;
            }
            sprod *= (a.x + a.y) + (a.z + a.w);
        }
        __syncthreads();   // protect Gf before next axis overwrites
    }

    // ---- phase 4: reductions ----
    float Ic = cp0 + cp1;
    #pragma unroll
    for (int m = 32; m; m >>= 1) Ic += __shfl_xor(Ic, m, 64);
    if (lane == 0) rI[wid] = Ic;

    if (wid == 0) {
        float s1 = (lane < 32) ? sprod : 0.0f;   // tasks 0,1 -> sum h1
        float s2 = (lane < 32) ? 0.0f : sprod;   // tasks 2,3 -> sum h2
        #pragma unroll
        for (int m = 32; m; m >>= 1) {
            s1 += __shfl_xor(s1, m, 64);
            s2 += __shfl_xor(s2, m, 64);
        }
        if (lane == 0) { sS1 = s1; sS2 = s2; }
    }
    __syncthreads();

    if (tid == 0) {
        const float I = rI[0] + rI[1] + rI[2] + rI[3];
        const float U = sS1 + sS2 - I + 1e-5f;
        out[0] = 1.0f - I / U;
    }
}

extern "C" void kernel_launch(void* const* d_in, const int* in_sizes, int n_in,
                              void* d_out, int out_size, void* d_ws, size_t ws_size,
                              hipStream_t stream)
{
    const float* pts1 = (const float*)d_in[0];   // [2,192,3]
    const float* w1   = (const float*)d_in[1];   // [2,192]
    const float* pts2 = (const float*)d_in[2];   // [2,192,3]
    const float* w2   = (const float*)d_in[3];   // [2,192]
    float* out = (float*)d_out;                  // scalar

    iou_sep<<<1, 256, 0, stream>>>(pts1, w1, pts2, w2, out);
}

// Round 7
// 29.907 us; speedup vs baseline: 4.0528x; 1.1012x over previous
//
#include <hip/hip_runtime.h>
#include <math.h>

#define RES 128
#define TOPK 16
#define NPTS 192
#define NQ 64                    // 4 tasks * 16 points
#define SIGMA_F (6.0f / 128.0f)
#define INV2S2 (1.0f / (2.0f * SIGMA_F * SIGMA_F))
#define GPITCH 132               // G row pitch in floats (128 + 4 pad, 16B-aligned)
#define NTHR 512                 // 8 waves, 2 per SIMD

// ---------------------------------------------------------------------------
// Single-block fused kernel using separability of the tensor-product grid:
//   I  = sum_v h1*h2 = sum_{q,q'} Cx[q][q'] * Cy[q][q'] * Cz[q][q']
//   S1 = sum_v h1    = sum_q Sx[q]*Sy[q]*Sz[q]   (w folded into axis-0 table)
//   U  = S1 + S2 - I ;  loss = 1 - I/(U + 1e-5)
// where C*[q][q'] = sum_i G*[q][i] * G*[q'][i] over the 128-point axis grid.
// Cross pairs: batch0 = task0 x task2, batch1 = task1 x task3 (16x16 each)
// -> 512 cross pairs total, exactly one per thread.
// 8 waves for latency hiding (the R6 version at 4 waves / 1 per SIMD was
// latency-bound: ~28us vs ~5us issue arithmetic).
// task: 0 = set1/b0, 1 = set1/b1, 2 = set2/b0, 3 = set2/b1
// ---------------------------------------------------------------------------
__global__ __launch_bounds__(NTHR) void iou_sep(
    const float* __restrict__ pts1, const float* __restrict__ w1,
    const float* __restrict__ pts2, const float* __restrict__ w2,
    float* __restrict__ out)
{
    __shared__ float Gf[NQ * GPITCH];   // 33.8 KB, rebuilt per axis
    __shared__ float swall[4][NPTS];
    __shared__ float sval[4][TOPK];
    __shared__ int   sidx[4][TOPK];
    __shared__ float sp[NQ][3];
    __shared__ float sw[NQ];
    __shared__ float sbound[6];         // lo x,y,z ; hi x,y,z
    __shared__ float rI[8];
    __shared__ float sS1, sS2;

    const int tid  = threadIdx.x;
    const int lane = tid & 63;
    const int wid  = tid >> 6;

    // ---- phase 1: rank-based top-16; waves 0-3, wave == task ----
    // (syncs hoisted out of the guard so waves 4-7 participate in barriers)
    float v0 = 0.0f, v1 = 0.0f, v2 = 0.0f;
    const float* pts = nullptr;
    if (wid < 4) {
        const int set = wid >> 1;
        const int b   = wid & 1;
        const float* w = (set ? w2 : w1) + b * NPTS;
        pts = (set ? pts2 : pts1) + b * NPTS * 3;
        v0 = w[lane];
        v1 = w[lane + 64];
        v2 = w[lane + 128];
        swall[wid][lane]       = v0;
        swall[wid][lane + 64]  = v1;
        swall[wid][lane + 128] = v2;
    }
    __syncthreads();

    if (wid < 4) {
        // rank among all 192: strictly-greater, or equal with lower index
        int r0 = 0, r1 = 0, r2 = 0;
        for (int j = 0; j < NPTS; ++j) {
            const float wj = swall[wid][j];
            r0 += (wj > v0) || (wj == v0 && j < lane);
            r1 += (wj > v1) || (wj == v1 && j < lane + 64);
            r2 += (wj > v2) || (wj == v2 && j < lane + 128);
        }
        if (r0 < TOPK) { sval[wid][r0] = v0; sidx[wid][r0] = lane; }
        if (r1 < TOPK) { sval[wid][r1] = v1; sidx[wid][r1] = lane + 64; }
        if (r2 < TOPK) { sval[wid][r2] = v2; sidx[wid][r2] = lane + 128; }
    }
    __syncthreads();

    if (wid < 4) {
        // renormalize + gather selected points
        float v = (lane < TOPK) ? sval[wid][lane] : 0.0f;
        float s = v;
        #pragma unroll
        for (int m = 32; m; m >>= 1) s += __shfl_xor(s, m, 64);
        if (lane < TOPK) {
            const int q   = wid * TOPK + lane;
            const int idx = sidx[wid][lane];
            sw[q]    = v / (s + 1e-5f);
            sp[q][0] = pts[idx * 3 + 0];
            sp[q][1] = pts[idx * 3 + 1];
            sp[q][2] = pts[idx * 3 + 2];
        }
    }
    __syncthreads();

    // ---- phase 2: per-axis bounds over all 64 selected points ----
    if (tid < 6) {
        const int  axis  = tid % 3;
        const bool ismax = tid >= 3;
        float r = sp[0][axis];
        for (int q = 1; q < NQ; ++q) {
            const float v = sp[q][axis];
            r = ismax ? fmaxf(r, v) : fminf(r, v);
        }
        sbound[tid] = ismax ? (r + 3.0f * SIGMA_F) : (r - 3.0f * SIGMA_F);
    }
    __syncthreads();

    // ---- phase 3: per-axis build + dot, multiplicative accumulate ----
    // Cross pair p = tid in [0,512): batch = p>>8, ql = (p>>4)&15, qr = p&15
    //   q = batch*16 + ql (set1),  q' = 32 + batch*16 + qr (set2)
    const int qa = ((tid >> 8) << 4) + ((tid >> 4) & 15);
    const int qb = 32 + ((tid >> 8) << 4) + (tid & 15);

    float cp = 1.0f;                 // cross-dot product across axes
    float sprod = 1.0f;              // self-sum product (tid < 64 only)

    #pragma unroll 1
    for (int axis = 0; axis < 3; ++axis) {
        // build G[q][i] for this axis (w folded in at axis 0); 16 iters/thread
        const float lo   = sbound[axis];
        const float step = (sbound[axis + 3] - lo) * (1.0f / 127.0f);
        for (int e = tid; e < NQ * RES; e += NTHR) {
            const int q = e >> 7;
            const int i = e & 127;
            const float c = lo + (float)i * step;
            const float d = c - sp[q][axis];
            float g = __expf(-d * d * INV2S2);
            if (axis == 0) g *= sw[q];
            Gf[q * GPITCH + i] = g;
        }
        __syncthreads();

        // one cross dot per thread
        {
            const float4* A = (const float4*)&Gf[qa * GPITCH];
            const float4* B = (const float4*)&Gf[qb * GPITCH];
            float4 a = {0,0,0,0};
            #pragma unroll 8
            for (int c = 0; c < 32; ++c) {
                const float4 x = A[c], y = B[c];
                a.x += x.x * y.x; a.y += x.y * y.y;
                a.z += x.z * y.z; a.w += x.w * y.w;
            }
            cp *= (a.x + a.y) + (a.z + a.w);
        }
        // self sum for q = tid (tid < 64 = all of wave 0)
        if (tid < 64) {
            const float4* A = (const float4*)&Gf[tid * GPITCH];
            float4 a = {0,0,0,0};
            #pragma unroll 8
            for (int c = 0; c < 32; ++c) {
                const float4 x = A[c];
                a.x += x.x; a.y += x.y; a.z += x.z; a.w += x.w;
            }
            sprod *= (a.x + a.y) + (a.z + a.w);
        }
        __syncthreads();   // protect Gf before next axis overwrites
    }

    // ---- phase 4: reductions ----
    float Ic = cp;
    #pragma unroll
    for (int m = 32; m; m >>= 1) Ic += __shfl_xor(Ic, m, 64);
    if (lane == 0) rI[wid] = Ic;

    if (wid == 0) {
        float s1 = (lane < 32) ? sprod : 0.0f;   // tasks 0,1 -> sum h1
        float s2 = (lane < 32) ? 0.0f : sprod;   // tasks 2,3 -> sum h2
        #pragma unroll
        for (int m = 32; m; m >>= 1) {
            s1 += __shfl_xor(s1, m, 64);
            s2 += __shfl_xor(s2, m, 64);
        }
        if (lane == 0) { sS1 = s1; sS2 = s2; }
    }
    __syncthreads();

    if (tid == 0) {
        float I = 0.0f;
        #pragma unroll
        for (int wv = 0; wv < 8; ++wv) I += rI[wv];
        const float U = sS1 + sS2 - I + 1e-5f;
        out[0] = 1.0f - I / U;
    }
}

extern "C" void kernel_launch(void* const* d_in, const int* in_sizes, int n_in,
                              void* d_out, int out_size, void* d_ws, size_t ws_size,
                              hipStream_t stream)
{
    const float* pts1 = (const float*)d_in[0];   // [2,192,3]
    const float* w1   = (const float*)d_in[1];   // [2,192]
    const float* pts2 = (const float*)d_in[2];   // [2,192,3]
    const float* w2   = (const float*)d_in[3];   // [2,192]
    float* out = (float*)d_out;                  // scalar

    iou_sep<<<1, NTHR, 0, stream>>>(pts1, w1, pts2, w2, out);
}